// Round 1
// baseline (913.943 us; speedup 1.0000x reference)
//
#include <hip/hip_runtime.h>
#include <math.h>

#define N_NODES 20000
#define N_EDGES 320000
#define MUL 64
#define NUM_BASIS 8
#define HID 64
#define NSPEC 4

// normalization constants
#define LIN_NORM     0.125f          // 1/sqrt(64)
#define INV_SQRT8    0.3535533906f   // 1/sqrt(8)
#define INV_HID      0.125f          // 1/sqrt(64)... wait sqrt(64)=8 -> 0.125
#define LIN2_NORM    0.08838834765f  // 1/sqrt(128)
#define SC_NORM      0.0625f         // 1/sqrt(64*4)
#define INV_NEIGH    0.0625f         // 1/16
#define INV_SQRT3    0.5773502692f
#define SILU_NORM    1.679177f

__device__ __forceinline__ float silu_n(float x) {
    float s = 1.0f / (1.0f + __expf(-x));
    return x * s * SILU_NORM;
}

// ---------------------------------------------------------------------------
// Kernel A: per-node lin1.  s = ns @ W_lin1_s * ln ; v_i = nv_i @ W_lin1_v * ln
// one wave per node; lane = output channel w.
// v stored planar: v[i][n][u]  (3 planes of N*64) for coalesced edge gathers.
// ---------------------------------------------------------------------------
__global__ __launch_bounds__(256) void k_node_lin1(
    const float* __restrict__ ns, const float* __restrict__ nv,
    const float* __restrict__ Ws, const float* __restrict__ Wv,
    float* __restrict__ s_out, float* __restrict__ v_out)
{
    int lane = threadIdx.x & 63;
    int n = (blockIdx.x * blockDim.x + threadIdx.x) >> 6;
    if (n >= N_NODES) return;
    const float* nsp = ns + (size_t)n * MUL;
    const float* nvp = nv + (size_t)n * MUL * 3;
    float as = 0.f, a0 = 0.f, a1 = 0.f, a2 = 0.f;
    #pragma unroll 8
    for (int u = 0; u < MUL; ++u) {
        float ws = Ws[u * MUL + lane];
        float wv = Wv[u * MUL + lane];
        as += nsp[u] * ws;
        a0 += nvp[u * 3 + 0] * wv;
        a1 += nvp[u * 3 + 1] * wv;
        a2 += nvp[u * 3 + 2] * wv;
    }
    s_out[(size_t)n * MUL + lane] = as * LIN_NORM;
    v_out[0 * (size_t)N_NODES * MUL + (size_t)n * MUL + lane] = a0 * LIN_NORM;
    v_out[1 * (size_t)N_NODES * MUL + (size_t)n * MUL + lane] = a1 * LIN_NORM;
    v_out[2 * (size_t)N_NODES * MUL + (size_t)n * MUL + lane] = a2 * LIN_NORM;
}

// ---------------------------------------------------------------------------
// Kernel B: per-edge MLP + tensor product + scatter-add.
// One wave handles EB=8 edges; lane = channel u.  Hidden activations live in
// registers (one per lane); cross-lane GEMV contractions via __shfl.
// ---------------------------------------------------------------------------
#define EB 8

__global__ __launch_bounds__(256) void k_edge(
    const float* __restrict__ emb, const float* __restrict__ sh,
    const int* __restrict__ esrc, const int* __restrict__ edst,
    const float* __restrict__ W0, const float* __restrict__ W1,
    const float* __restrict__ W2,
    const float* __restrict__ s_in, const float* __restrict__ v_in,
    float* __restrict__ s_agg, float* __restrict__ v_agg)
{
    int lane = threadIdx.x & 63;
    int gwave = (blockIdx.x * blockDim.x + threadIdx.x) >> 6;
    int base = gwave * EB;
    if (base >= N_EDGES) return;

    // ---- fc0: h0[e][lane] = silu_n( (emb[e] . W0[:,lane]) / sqrt(8) )
    float acc[EB];
    #pragma unroll
    for (int e = 0; e < EB; ++e) acc[e] = 0.f;
    #pragma unroll
    for (int k = 0; k < NUM_BASIS; ++k) {
        float wv = W0[k * HID + lane];
        #pragma unroll
        for (int e = 0; e < EB; ++e)
            acc[e] += emb[(size_t)(base + e) * NUM_BASIS + k] * wv;
    }
    float h[EB];
    #pragma unroll
    for (int e = 0; e < EB; ++e) h[e] = silu_n(acc[e] * INV_SQRT8);

    // ---- fc1: h1 = silu_n( h0 @ W1 / 8 )
    #pragma unroll
    for (int e = 0; e < EB; ++e) acc[e] = 0.f;
    #pragma unroll 4
    for (int k = 0; k < HID; ++k) {
        float wv = W1[k * HID + lane];
        #pragma unroll
        for (int e = 0; e < EB; ++e)
            acc[e] += __shfl(h[e], k) * wv;
    }
    #pragma unroll
    for (int e = 0; e < EB; ++e) h[e] = silu_n(acc[e] * 0.125f);

    // ---- fc2: w = h1 @ W2 / 8 ;  4 output groups of 64
    float aw0[EB], aw1[EB], aw2[EB], aw3[EB];
    #pragma unroll
    for (int e = 0; e < EB; ++e) { aw0[e] = 0.f; aw1[e] = 0.f; aw2[e] = 0.f; aw3[e] = 0.f; }
    #pragma unroll 2
    for (int k = 0; k < HID; ++k) {
        float w0 = W2[k * 256 + lane];
        float w1 = W2[k * 256 + 64 + lane];
        float w2 = W2[k * 256 + 128 + lane];
        float w3 = W2[k * 256 + 192 + lane];
        #pragma unroll
        for (int e = 0; e < EB; ++e) {
            float hv = __shfl(h[e], k);
            aw0[e] += hv * w0;
            aw1[e] += hv * w1;
            aw2[e] += hv * w2;
            aw3[e] += hv * w3;
        }
    }

    // ---- tensor product + scatter
    #pragma unroll 1
    for (int e = 0; e < EB; ++e) {
        int eid = base + e;
        int src = esrc[eid];
        int dst = edst[eid];
        float y0 = sh[(size_t)eid * 4 + 0];
        float yx = sh[(size_t)eid * 4 + 1];
        float yy = sh[(size_t)eid * 4 + 2];
        float yz = sh[(size_t)eid * 4 + 3];
        float se = s_in[(size_t)src * MUL + lane];
        float v0 = v_in[0 * (size_t)N_NODES * MUL + (size_t)src * MUL + lane];
        float v1 = v_in[1 * (size_t)N_NODES * MUL + (size_t)src * MUL + lane];
        float v2 = v_in[2 * (size_t)N_NODES * MUL + (size_t)src * MUL + lane];
        float wA = aw0[e] * 0.125f;
        float wB = aw1[e] * 0.125f;
        float wC = aw2[e] * 0.125f;
        float wD = aw3[e] * 0.125f;

        float oA = wA * se * y0 * INV_NEIGH;
        float dot = v0 * yx + v1 * yy + v2 * yz;
        float oD = wD * dot * INV_SQRT3 * INV_NEIGH;
        atomicAdd(&s_agg[(size_t)dst * 128 + lane], oA);
        atomicAdd(&s_agg[(size_t)dst * 128 + 64 + lane], oD);

        float bB = wB * se * INV_NEIGH;
        atomicAdd(&v_agg[0 * (size_t)N_NODES * 128 + (size_t)dst * 128 + lane], bB * yx);
        atomicAdd(&v_agg[1 * (size_t)N_NODES * 128 + (size_t)dst * 128 + lane], bB * yy);
        atomicAdd(&v_agg[2 * (size_t)N_NODES * 128 + (size_t)dst * 128 + lane], bB * yz);

        float bC = wC * y0 * INV_NEIGH;
        atomicAdd(&v_agg[0 * (size_t)N_NODES * 128 + (size_t)dst * 128 + 64 + lane], bC * v0);
        atomicAdd(&v_agg[1 * (size_t)N_NODES * 128 + (size_t)dst * 128 + 64 + lane], bC * v1);
        atomicAdd(&v_agg[2 * (size_t)N_NODES * 128 + (size_t)dst * 128 + 64 + lane], bC * v2);
    }
}

// ---------------------------------------------------------------------------
// Kernel C: per-node epilogue.  s_h = s_agg@Wl2s*l2n + sc_s ; v_h similar.
// One wave per NB=4 nodes (register-blocked so 288KB of weights are read once
// per 4 nodes).  Self-connection einsums fused (never materialized).
// ---------------------------------------------------------------------------
#define NB 4

__global__ __launch_bounds__(256) void k_node_out(
    const float* __restrict__ ns, const float* __restrict__ nv,
    const float* __restrict__ na,
    const float* __restrict__ Wl2s, const float* __restrict__ Wl2v,
    const float* __restrict__ Wscs, const float* __restrict__ Wscv,
    const float* __restrict__ s_agg, const float* __restrict__ v_agg,
    float* __restrict__ out)
{
    int lane = threadIdx.x & 63;
    int gwave = (blockIdx.x * blockDim.x + threadIdx.x) >> 6;
    int n0 = gwave * NB;
    if (n0 >= N_NODES) return;

    float sA[NB], sB[NB], vh[NB][3];
    #pragma unroll
    for (int j = 0; j < NB; ++j) {
        sA[j] = 0.f; sB[j] = 0.f;
        vh[j][0] = 0.f; vh[j][1] = 0.f; vh[j][2] = 0.f;
    }

    // lin2_s: 128 -> (lane, 64+lane)
    #pragma unroll 4
    for (int u = 0; u < 128; ++u) {
        float w1 = Wl2s[u * 128 + lane];
        float w2 = Wl2s[u * 128 + 64 + lane];
        #pragma unroll
        for (int j = 0; j < NB; ++j) {
            float a = s_agg[(size_t)(n0 + j) * 128 + u];
            sA[j] += a * w1;
            sB[j] += a * w2;
        }
    }
    // lin2_v
    #pragma unroll 4
    for (int u = 0; u < 128; ++u) {
        float wv = Wl2v[u * 64 + lane];
        #pragma unroll
        for (int j = 0; j < NB; ++j) {
            vh[j][0] += v_agg[0 * (size_t)N_NODES * 128 + (size_t)(n0 + j) * 128 + u] * wv;
            vh[j][1] += v_agg[1 * (size_t)N_NODES * 128 + (size_t)(n0 + j) * 128 + u] * wv;
            vh[j][2] += v_agg[2 * (size_t)N_NODES * 128 + (size_t)(n0 + j) * 128 + u] * wv;
        }
    }
    #pragma unroll
    for (int j = 0; j < NB; ++j) {
        sA[j] *= LIN2_NORM; sB[j] *= LIN2_NORM;
        vh[j][0] *= LIN2_NORM; vh[j][1] *= LIN2_NORM; vh[j][2] *= LIN2_NORM;
    }

    // self-connection, fused (adds sc_s / sc_v contributions)
    float pa[NB][4];
    #pragma unroll
    for (int j = 0; j < NB; ++j)
        #pragma unroll
        for (int q = 0; q < 4; ++q)
            pa[j][q] = na[(size_t)(n0 + j) * 4 + q] * SC_NORM;

    #pragma unroll 2
    for (int u = 0; u < 64; ++u) {
        float su[NB], vu[NB][3];
        #pragma unroll
        for (int j = 0; j < NB; ++j) {
            su[j] = ns[(size_t)(n0 + j) * 64 + u];
            vu[j][0] = nv[(size_t)(n0 + j) * 192 + u * 3 + 0];
            vu[j][1] = nv[(size_t)(n0 + j) * 192 + u * 3 + 1];
            vu[j][2] = nv[(size_t)(n0 + j) * 192 + u * 3 + 2];
        }
        #pragma unroll
        for (int q = 0; q < 4; ++q) {
            int idx = u * 4 + q;
            float wss1 = Wscs[idx * 128 + lane];
            float wss2 = Wscs[idx * 128 + 64 + lane];
            float wsv  = Wscv[idx * 64 + lane];
            #pragma unroll
            for (int j = 0; j < NB; ++j) {
                float t = su[j] * pa[j][q];
                sA[j] += t * wss1;
                sB[j] += t * wss2;
                vh[j][0] += vu[j][0] * pa[j][q] * wsv;
                vh[j][1] += vu[j][1] * pa[j][q] * wsv;
                vh[j][2] += vu[j][2] * pa[j][q] * wsv;
            }
        }
    }

    // epilogue + store
    #pragma unroll
    for (int j = 0; j < NB; ++j) {
        int n = n0 + j;
        float os = silu_n(sA[j]);
        float g  = silu_n(sB[j]);
        out[(size_t)n * 256 + lane] = os;
        out[(size_t)n * 256 + 64 + lane * 3 + 0] = g * vh[j][0];
        out[(size_t)n * 256 + 64 + lane * 3 + 1] = g * vh[j][1];
        out[(size_t)n * 256 + 64 + lane * 3 + 2] = g * vh[j][2];
    }
}

// ---------------------------------------------------------------------------
extern "C" void kernel_launch(void* const* d_in, const int* in_sizes, int n_in,
                              void* d_out, int out_size, void* d_ws, size_t ws_size,
                              hipStream_t stream)
{
    const float* node_scalars = (const float*)d_in[0];
    const float* node_vectors = (const float*)d_in[1];
    const float* node_attr    = (const float*)d_in[2];
    const float* edge_sh      = (const float*)d_in[3];
    const float* edge_emb     = (const float*)d_in[4];
    const int*   edge_src     = (const int*)d_in[5];
    const int*   edge_dst     = (const int*)d_in[6];
    const float* W_lin1_s = (const float*)d_in[7];
    const float* W_lin1_v = (const float*)d_in[8];
    const float* W_fc0    = (const float*)d_in[9];
    const float* W_fc1    = (const float*)d_in[10];
    const float* W_fc2    = (const float*)d_in[11];
    const float* W_lin2_s = (const float*)d_in[12];
    const float* W_lin2_v = (const float*)d_in[13];
    const float* W_sc_s   = (const float*)d_in[14];
    const float* W_sc_v   = (const float*)d_in[15];
    float* out = (float*)d_out;

    // workspace layout (floats)
    float* ws    = (float*)d_ws;
    float* s_buf = ws;                                   // N*64
    float* v_buf = s_buf + (size_t)N_NODES * 64;         // 3*N*64
    float* s_agg = v_buf + 3 * (size_t)N_NODES * 64;     // N*128
    float* v_agg = s_agg + (size_t)N_NODES * 128;        // 3*N*128

    // zero the aggregation buffers (s_agg and v_agg are contiguous)
    size_t agg_bytes = (size_t)N_NODES * 512 * sizeof(float);
    hipMemsetAsync(s_agg, 0, agg_bytes, stream);

    // A: node lin1  (one wave per node)
    {
        int waves = N_NODES;
        int blocks = (waves + 3) / 4;
        k_node_lin1<<<blocks, 256, 0, stream>>>(node_scalars, node_vectors,
                                                W_lin1_s, W_lin1_v, s_buf, v_buf);
    }
    // B: edges (one wave per 8 edges)
    {
        int waves = (N_EDGES + EB - 1) / EB;   // 40000
        int blocks = (waves + 3) / 4;          // 10000
        k_edge<<<blocks, 256, 0, stream>>>(edge_emb, edge_sh, edge_src, edge_dst,
                                           W_fc0, W_fc1, W_fc2,
                                           s_buf, v_buf, s_agg, v_agg);
    }
    // C: node epilogue (one wave per 4 nodes)
    {
        int waves = (N_NODES + NB - 1) / NB;   // 5000
        int blocks = (waves + 3) / 4;          // 1250
        k_node_out<<<blocks, 256, 0, stream>>>(node_scalars, node_vectors, node_attr,
                                               W_lin2_s, W_lin2_v, W_sc_s, W_sc_v,
                                               s_agg, v_agg, out);
    }
}

// Round 2
// 875.124 us; speedup vs baseline: 1.0444x; 1.0444x over previous
//
#include <hip/hip_runtime.h>
#include <math.h>

#define N_NODES 20000
#define N_EDGES 320000
#define MUL 64
#define NUM_BASIS 8
#define HID 64
#define NSPEC 4

#define LIN_NORM     0.125f          // 1/sqrt(64)
#define INV_SQRT8    0.3535533906f   // 1/sqrt(8)
#define LIN2_NORM    0.08838834765f  // 1/sqrt(128)
#define SC_NORM      0.0625f         // 1/sqrt(64*4)
#define INV_NEIGH    0.0625f         // 1/16
#define INV_SQRT3    0.5773502692f
#define SILU_NORM    1.679177f

__device__ __forceinline__ float silu_n(float x) {
    float s = 1.0f / (1.0f + __expf(-x));
    return x * s * SILU_NORM;
}

// ---------------------------------------------------------------------------
// CSR build: histogram -> 1-block scan -> scatter (permutation sorted by dst)
// ---------------------------------------------------------------------------
__global__ __launch_bounds__(256) void k_hist(const int* __restrict__ edst,
                                              int* __restrict__ counts)
{
    int e = blockIdx.x * blockDim.x + threadIdx.x;
    if (e < N_EDGES) atomicAdd(&counts[edst[e]], 1);
}

#define SCAN_T 1024
__global__ __launch_bounds__(SCAN_T) void k_scan(const int* __restrict__ counts,
                                                 int* __restrict__ cursor)
{
    __shared__ int part[SCAN_T];
    int t = threadIdx.x;
    const int CH = (N_NODES + SCAN_T - 1) / SCAN_T;   // 20
    int b0 = t * CH;
    int s = 0;
    for (int i = 0; i < CH; ++i) {
        int idx = b0 + i;
        if (idx < N_NODES) s += counts[idx];
    }
    part[t] = s;
    __syncthreads();
    // Hillis-Steele inclusive scan
    for (int off = 1; off < SCAN_T; off <<= 1) {
        int v = (t >= off) ? part[t - off] : 0;
        __syncthreads();
        part[t] += v;
        __syncthreads();
    }
    int run = (t == 0) ? 0 : part[t - 1];
    for (int i = 0; i < CH; ++i) {
        int idx = b0 + i;
        if (idx < N_NODES) {
            cursor[idx] = run;
            run += counts[idx];
        }
    }
}

__global__ __launch_bounds__(256) void k_fill(const int* __restrict__ edst,
                                              int* __restrict__ cursor,
                                              int* __restrict__ elist,
                                              int* __restrict__ dlist)
{
    int e = blockIdx.x * blockDim.x + threadIdx.x;
    if (e < N_EDGES) {
        int d = edst[e];
        int pos = atomicAdd(&cursor[d], 1);
        elist[pos] = e;
        dlist[pos] = d;
    }
}

// ---------------------------------------------------------------------------
// Kernel A: per-node lin1 (shfl version: coalesced act loads, no broadcasts)
// v stored planar: v[p][n][u]
// ---------------------------------------------------------------------------
__global__ __launch_bounds__(256) void k_node_lin1(
    const float* __restrict__ ns, const float* __restrict__ nv,
    const float* __restrict__ Ws, const float* __restrict__ Wv,
    float* __restrict__ s_out, float* __restrict__ v_out)
{
    int lane = threadIdx.x & 63;
    int n = (blockIdx.x * blockDim.x + threadIdx.x) >> 6;
    if (n >= N_NODES) return;
    float s_r  = ns[(size_t)n * 64 + lane];
    float v_r0 = nv[(size_t)n * 192 + lane * 3 + 0];
    float v_r1 = nv[(size_t)n * 192 + lane * 3 + 1];
    float v_r2 = nv[(size_t)n * 192 + lane * 3 + 2];
    float as = 0.f, a0 = 0.f, a1 = 0.f, a2 = 0.f;
    #pragma unroll 8
    for (int u = 0; u < 64; ++u) {
        float ws = Ws[u * 64 + lane];
        float wv = Wv[u * 64 + lane];
        as += __shfl(s_r, u)  * ws;
        a0 += __shfl(v_r0, u) * wv;
        a1 += __shfl(v_r1, u) * wv;
        a2 += __shfl(v_r2, u) * wv;
    }
    s_out[(size_t)n * 64 + lane] = as * LIN_NORM;
    v_out[0 * (size_t)N_NODES * 64 + (size_t)n * 64 + lane] = a0 * LIN_NORM;
    v_out[1 * (size_t)N_NODES * 64 + (size_t)n * 64 + lane] = a1 * LIN_NORM;
    v_out[2 * (size_t)N_NODES * 64 + (size_t)n * 64 + lane] = a2 * LIN_NORM;
}

// ---------------------------------------------------------------------------
// Kernel B: edge MLP + tensor product over DST-SORTED edge permutation.
// EB=8 edges per wave; consecutive edges mostly share dst -> register
// run-merging cuts atomics ~5x and makes the rest L2-local.
// ---------------------------------------------------------------------------
#define EB 8

__global__ __launch_bounds__(256) void k_edge_sorted(
    const float* __restrict__ emb, const float* __restrict__ sh,
    const int* __restrict__ esrc,
    const int* __restrict__ elist, const int* __restrict__ dlist,
    const float* __restrict__ W0, const float* __restrict__ W1,
    const float* __restrict__ W2,
    const float* __restrict__ s_in, const float* __restrict__ v_in,
    float* __restrict__ s_agg, float* __restrict__ v_agg)
{
    const size_t NP2 = (size_t)N_NODES * 128;
    const size_t NV  = (size_t)N_NODES * 64;
    int lane = threadIdx.x & 63;
    int gwave = (blockIdx.x * blockDim.x + threadIdx.x) >> 6;
    int base = gwave * EB;
    if (base >= N_EDGES) return;

    int eids[EB], dsts[EB];
    #pragma unroll
    for (int e = 0; e < EB; ++e) {
        eids[e] = __builtin_amdgcn_readfirstlane(elist[base + e]);
        dsts[e] = __builtin_amdgcn_readfirstlane(dlist[base + e]);
    }

    // ---- fc0
    float acc[EB];
    #pragma unroll
    for (int e = 0; e < EB; ++e) acc[e] = 0.f;
    #pragma unroll
    for (int k = 0; k < NUM_BASIS; ++k) {
        float wv = W0[k * HID + lane];
        #pragma unroll
        for (int e = 0; e < EB; ++e)
            acc[e] += emb[(size_t)eids[e] * NUM_BASIS + k] * wv;
    }
    float h[EB];
    #pragma unroll
    for (int e = 0; e < EB; ++e) h[e] = silu_n(acc[e] * INV_SQRT8);

    // ---- fc1
    #pragma unroll
    for (int e = 0; e < EB; ++e) acc[e] = 0.f;
    #pragma unroll 4
    for (int k = 0; k < HID; ++k) {
        float wv = W1[k * HID + lane];
        #pragma unroll
        for (int e = 0; e < EB; ++e)
            acc[e] += __shfl(h[e], k) * wv;
    }
    #pragma unroll
    for (int e = 0; e < EB; ++e) h[e] = silu_n(acc[e] * 0.125f);

    // ---- fc2 (4 output groups of 64)
    float aw0[EB], aw1[EB], aw2[EB], aw3[EB];
    #pragma unroll
    for (int e = 0; e < EB; ++e) { aw0[e] = 0.f; aw1[e] = 0.f; aw2[e] = 0.f; aw3[e] = 0.f; }
    #pragma unroll 2
    for (int k = 0; k < HID; ++k) {
        float w0 = W2[k * 256 + lane];
        float w1 = W2[k * 256 + 64 + lane];
        float w2 = W2[k * 256 + 128 + lane];
        float w3 = W2[k * 256 + 192 + lane];
        #pragma unroll
        for (int e = 0; e < EB; ++e) {
            float hv = __shfl(h[e], k);
            aw0[e] += hv * w0;
            aw1[e] += hv * w1;
            aw2[e] += hv * w2;
            aw3[e] += hv * w3;
        }
    }

    // ---- tensor product + run-merged scatter
    float accA = 0.f, accD = 0.f;
    float aB0 = 0.f, aB1 = 0.f, aB2 = 0.f;
    float aC0 = 0.f, aC1 = 0.f, aC2 = 0.f;

    auto flush = [&](int d) {
        size_t db = (size_t)d * 128;
        atomicAdd(&s_agg[db + lane],              accA * INV_NEIGH);
        atomicAdd(&s_agg[db + 64 + lane],         accD * INV_NEIGH);
        atomicAdd(&v_agg[0 * NP2 + db + lane],      aB0 * INV_NEIGH);
        atomicAdd(&v_agg[1 * NP2 + db + lane],      aB1 * INV_NEIGH);
        atomicAdd(&v_agg[2 * NP2 + db + lane],      aB2 * INV_NEIGH);
        atomicAdd(&v_agg[0 * NP2 + db + 64 + lane], aC0 * INV_NEIGH);
        atomicAdd(&v_agg[1 * NP2 + db + 64 + lane], aC1 * INV_NEIGH);
        atomicAdd(&v_agg[2 * NP2 + db + 64 + lane], aC2 * INV_NEIGH);
        accA = accD = aB0 = aB1 = aB2 = aC0 = aC1 = aC2 = 0.f;
    };

    int cur = dsts[0];
    const float4* sh4 = (const float4*)sh;
    #pragma unroll
    for (int e = 0; e < EB; ++e) {
        if (dsts[e] != cur) { flush(cur); cur = dsts[e]; }
        int eid = eids[e];
        int src = __builtin_amdgcn_readfirstlane(esrc[eid]);
        float4 y = sh4[eid];
        float se = s_in[(size_t)src * 64 + lane];
        float v0 = v_in[0 * NV + (size_t)src * 64 + lane];
        float v1 = v_in[1 * NV + (size_t)src * 64 + lane];
        float v2 = v_in[2 * NV + (size_t)src * 64 + lane];
        float wA = aw0[e] * 0.125f;
        float wB = aw1[e] * 0.125f;
        float wC = aw2[e] * 0.125f;
        float wD = aw3[e] * 0.125f;

        accA += wA * se * y.x;
        float dot = v0 * y.y + v1 * y.z + v2 * y.w;
        accD += wD * dot * INV_SQRT3;
        float bB = wB * se;
        aB0 += bB * y.y;
        aB1 += bB * y.z;
        aB2 += bB * y.w;
        float bC = wC * y.x;
        aC0 += bC * v0;
        aC1 += bC * v1;
        aC2 += bC * v2;
    }
    flush(cur);
}

// ---------------------------------------------------------------------------
// Kernel C: per-node epilogue (shfl version). NB=4 nodes per wave.
// ---------------------------------------------------------------------------
#define NB 4

__global__ __launch_bounds__(256) void k_node_out(
    const float* __restrict__ ns, const float* __restrict__ nv,
    const float* __restrict__ na,
    const float* __restrict__ Wl2s, const float* __restrict__ Wl2v,
    const float* __restrict__ Wscs, const float* __restrict__ Wscv,
    const float* __restrict__ s_agg, const float* __restrict__ v_agg,
    float* __restrict__ out)
{
    const size_t NP2 = (size_t)N_NODES * 128;
    int lane = threadIdx.x & 63;
    int gwave = (blockIdx.x * blockDim.x + threadIdx.x) >> 6;
    int n0 = gwave * NB;
    if (n0 >= N_NODES) return;

    // coalesced activation preloads (lane = channel)
    float a_lo[NB], a_hi[NB];
    float b_lo[3][NB], b_hi[3][NB];
    float su_r[NB], vu_r[3][NB];
    float pa[NB][4];
    #pragma unroll
    for (int j = 0; j < NB; ++j) {
        size_t nj = n0 + j;
        a_lo[j] = s_agg[nj * 128 + lane];
        a_hi[j] = s_agg[nj * 128 + 64 + lane];
        #pragma unroll
        for (int p = 0; p < 3; ++p) {
            b_lo[p][j] = v_agg[p * NP2 + nj * 128 + lane];
            b_hi[p][j] = v_agg[p * NP2 + nj * 128 + 64 + lane];
            vu_r[p][j] = nv[nj * 192 + lane * 3 + p];
        }
        su_r[j] = ns[nj * 64 + lane];
        #pragma unroll
        for (int q = 0; q < 4; ++q)
            pa[j][q] = na[nj * 4 + q] * SC_NORM;
    }

    float sA[NB], sB[NB], vh[NB][3];
    #pragma unroll
    for (int j = 0; j < NB; ++j) {
        sA[j] = 0.f; sB[j] = 0.f;
        vh[j][0] = 0.f; vh[j][1] = 0.f; vh[j][2] = 0.f;
    }

    // lin2_s
    #pragma unroll 4
    for (int u = 0; u < 64; ++u) {
        float w1 = Wl2s[u * 128 + lane];
        float w2 = Wl2s[u * 128 + 64 + lane];
        #pragma unroll
        for (int j = 0; j < NB; ++j) {
            float av = __shfl(a_lo[j], u);
            sA[j] += av * w1; sB[j] += av * w2;
        }
    }
    #pragma unroll 4
    for (int u = 0; u < 64; ++u) {
        float w1 = Wl2s[(64 + u) * 128 + lane];
        float w2 = Wl2s[(64 + u) * 128 + 64 + lane];
        #pragma unroll
        for (int j = 0; j < NB; ++j) {
            float av = __shfl(a_hi[j], u);
            sA[j] += av * w1; sB[j] += av * w2;
        }
    }
    // lin2_v
    #pragma unroll 4
    for (int u = 0; u < 64; ++u) {
        float wv = Wl2v[u * 64 + lane];
        #pragma unroll
        for (int j = 0; j < NB; ++j) {
            vh[j][0] += __shfl(b_lo[0][j], u) * wv;
            vh[j][1] += __shfl(b_lo[1][j], u) * wv;
            vh[j][2] += __shfl(b_lo[2][j], u) * wv;
        }
    }
    #pragma unroll 4
    for (int u = 0; u < 64; ++u) {
        float wv = Wl2v[(64 + u) * 64 + lane];
        #pragma unroll
        for (int j = 0; j < NB; ++j) {
            vh[j][0] += __shfl(b_hi[0][j], u) * wv;
            vh[j][1] += __shfl(b_hi[1][j], u) * wv;
            vh[j][2] += __shfl(b_hi[2][j], u) * wv;
        }
    }
    #pragma unroll
    for (int j = 0; j < NB; ++j) {
        sA[j] *= LIN2_NORM; sB[j] *= LIN2_NORM;
        vh[j][0] *= LIN2_NORM; vh[j][1] *= LIN2_NORM; vh[j][2] *= LIN2_NORM;
    }

    // self-connection (fused)
    #pragma unroll 2
    for (int u = 0; u < 64; ++u) {
        float suv[NB], vuv[3][NB];
        #pragma unroll
        for (int j = 0; j < NB; ++j) {
            suv[j] = __shfl(su_r[j], u);
            vuv[0][j] = __shfl(vu_r[0][j], u);
            vuv[1][j] = __shfl(vu_r[1][j], u);
            vuv[2][j] = __shfl(vu_r[2][j], u);
        }
        #pragma unroll
        for (int q = 0; q < 4; ++q) {
            int idx = u * 4 + q;
            float wss1 = Wscs[idx * 128 + lane];
            float wss2 = Wscs[idx * 128 + 64 + lane];
            float wsv  = Wscv[idx * 64 + lane];
            #pragma unroll
            for (int j = 0; j < NB; ++j) {
                float t = suv[j] * pa[j][q];
                sA[j] += t * wss1;
                sB[j] += t * wss2;
                float tq = pa[j][q] * wsv;
                vh[j][0] += vuv[0][j] * tq;
                vh[j][1] += vuv[1][j] * tq;
                vh[j][2] += vuv[2][j] * tq;
            }
        }
    }

    // epilogue + store
    #pragma unroll
    for (int j = 0; j < NB; ++j) {
        int n = n0 + j;
        float os = silu_n(sA[j]);
        float g  = silu_n(sB[j]);
        out[(size_t)n * 256 + lane] = os;
        out[(size_t)n * 256 + 64 + lane * 3 + 0] = g * vh[j][0];
        out[(size_t)n * 256 + 64 + lane * 3 + 1] = g * vh[j][1];
        out[(size_t)n * 256 + 64 + lane * 3 + 2] = g * vh[j][2];
    }
}

// ---------------------------------------------------------------------------
extern "C" void kernel_launch(void* const* d_in, const int* in_sizes, int n_in,
                              void* d_out, int out_size, void* d_ws, size_t ws_size,
                              hipStream_t stream)
{
    const float* node_scalars = (const float*)d_in[0];
    const float* node_vectors = (const float*)d_in[1];
    const float* node_attr    = (const float*)d_in[2];
    const float* edge_sh      = (const float*)d_in[3];
    const float* edge_emb     = (const float*)d_in[4];
    const int*   edge_src     = (const int*)d_in[5];
    const int*   edge_dst     = (const int*)d_in[6];
    const float* W_lin1_s = (const float*)d_in[7];
    const float* W_lin1_v = (const float*)d_in[8];
    const float* W_fc0    = (const float*)d_in[9];
    const float* W_fc1    = (const float*)d_in[10];
    const float* W_fc2    = (const float*)d_in[11];
    const float* W_lin2_s = (const float*)d_in[12];
    const float* W_lin2_v = (const float*)d_in[13];
    const float* W_sc_s   = (const float*)d_in[14];
    const float* W_sc_v   = (const float*)d_in[15];
    float* out = (float*)d_out;

    // workspace layout
    float* ws    = (float*)d_ws;
    float* s_buf = ws;                                    // N*64
    float* v_buf = s_buf + (size_t)N_NODES * 64;          // 3*N*64
    float* s_agg = v_buf + 3 * (size_t)N_NODES * 64;      // N*128
    float* v_agg = s_agg + (size_t)N_NODES * 128;         // 3*N*128
    int*   counts = (int*)(v_agg + 3 * (size_t)N_NODES * 128);  // N
    int*   cursor = counts + N_NODES;                     // N
    int*   elist  = cursor + N_NODES;                     // E
    int*   dlist  = elist + N_EDGES;                      // E

    // zero aggregation buffers (contiguous) + histogram counters
    hipMemsetAsync(s_agg, 0, (size_t)N_NODES * 512 * sizeof(float), stream);
    hipMemsetAsync(counts, 0, (size_t)N_NODES * sizeof(int), stream);

    // CSR build
    {
        int blocks = (N_EDGES + 255) / 256;
        k_hist<<<blocks, 256, 0, stream>>>(edge_dst, counts);
        k_scan<<<1, SCAN_T, 0, stream>>>(counts, cursor);
        k_fill<<<blocks, 256, 0, stream>>>(edge_dst, cursor, elist, dlist);
    }
    // A: node lin1
    {
        int blocks = (N_NODES + 3) / 4;
        k_node_lin1<<<blocks, 256, 0, stream>>>(node_scalars, node_vectors,
                                                W_lin1_s, W_lin1_v, s_buf, v_buf);
    }
    // B: edges over sorted permutation
    {
        int waves = (N_EDGES + EB - 1) / EB;   // 40000
        int blocks = (waves + 3) / 4;          // 10000
        k_edge_sorted<<<blocks, 256, 0, stream>>>(edge_emb, edge_sh, edge_src,
                                                  elist, dlist,
                                                  W_fc0, W_fc1, W_fc2,
                                                  s_buf, v_buf, s_agg, v_agg);
    }
    // C: node epilogue
    {
        int waves = (N_NODES + NB - 1) / NB;   // 5000
        int blocks = (waves + 3) / 4;          // 1250
        k_node_out<<<blocks, 256, 0, stream>>>(node_scalars, node_vectors, node_attr,
                                               W_lin2_s, W_lin2_v, W_sc_s, W_sc_v,
                                               s_agg, v_agg, out);
    }
}

// Round 3
// 702.797 us; speedup vs baseline: 1.3004x; 1.2452x over previous
//
#include <hip/hip_runtime.h>
#include <math.h>

#define N_NODES 20000
#define N_EDGES 320000
#define MUL 64
#define NUM_BASIS 8
#define HID 64
#define NSPEC 4

#define LIN_NORM     0.125f          // 1/sqrt(64)
#define INV_SQRT8    0.3535533906f   // 1/sqrt(8)
#define LIN2_NORM    0.08838834765f  // 1/sqrt(128)
#define SC_NORM      0.0625f         // 1/sqrt(64*4)
#define INV_NEIGH    0.0625f         // 1/16
#define INV_SQRT3    0.5773502692f
#define SILU_NORM    1.679177f

__device__ __forceinline__ float silu_n(float x) {
    float s = 1.0f / (1.0f + __expf(-x));
    return x * s * SILU_NORM;
}

// broadcast from (uniform) lane l without touching the LDS pipe:
// v_readlane_b32 — lane select may be SGPR, so rolled loops are fine.
__device__ __forceinline__ float bcast(float x, int l) {
    return __uint_as_float(__builtin_amdgcn_readlane(__float_as_uint(x), l));
}

// ---------------------------------------------------------------------------
// CSR build: histogram -> 1-block scan -> scatter (permutation sorted by dst)
// ---------------------------------------------------------------------------
__global__ __launch_bounds__(256) void k_hist(const int* __restrict__ edst,
                                              int* __restrict__ counts)
{
    int e = blockIdx.x * blockDim.x + threadIdx.x;
    if (e < N_EDGES) atomicAdd(&counts[edst[e]], 1);
}

#define SCAN_T 1024
__global__ __launch_bounds__(SCAN_T) void k_scan(const int* __restrict__ counts,
                                                 int* __restrict__ cursor)
{
    __shared__ int part[SCAN_T];
    int t = threadIdx.x;
    const int CH = (N_NODES + SCAN_T - 1) / SCAN_T;   // 20
    int b0 = t * CH;
    int s = 0;
    for (int i = 0; i < CH; ++i) {
        int idx = b0 + i;
        if (idx < N_NODES) s += counts[idx];
    }
    part[t] = s;
    __syncthreads();
    for (int off = 1; off < SCAN_T; off <<= 1) {
        int v = (t >= off) ? part[t - off] : 0;
        __syncthreads();
        part[t] += v;
        __syncthreads();
    }
    int run = (t == 0) ? 0 : part[t - 1];
    for (int i = 0; i < CH; ++i) {
        int idx = b0 + i;
        if (idx < N_NODES) {
            cursor[idx] = run;
            run += counts[idx];
        }
    }
}

__global__ __launch_bounds__(256) void k_fill(const int* __restrict__ edst,
                                              int* __restrict__ cursor,
                                              int* __restrict__ elist,
                                              int* __restrict__ dlist)
{
    int e = blockIdx.x * blockDim.x + threadIdx.x;
    if (e < N_EDGES) {
        int d = edst[e];
        int pos = atomicAdd(&cursor[d], 1);
        elist[pos] = e;
        dlist[pos] = d;
    }
}

// ---------------------------------------------------------------------------
// Kernel A: per-node lin1.  Activations read at wave-uniform addresses
// (scalar loads); weights lane-coalesced. No shuffles.
// v stored planar: v[p][n][u]
// ---------------------------------------------------------------------------
__global__ __launch_bounds__(256) void k_node_lin1(
    const float* __restrict__ ns, const float* __restrict__ nv,
    const float* __restrict__ Ws, const float* __restrict__ Wv,
    float* __restrict__ s_out, float* __restrict__ v_out)
{
    int lane = threadIdx.x & 63;
    int gwave = (blockIdx.x * blockDim.x + threadIdx.x) >> 6;
    int n = __builtin_amdgcn_readfirstlane(gwave);
    if (n >= N_NODES) return;
    const float* nsp = ns + (size_t)n * 64;
    const float* nvp = nv + (size_t)n * 192;
    float as = 0.f, a0 = 0.f, a1 = 0.f, a2 = 0.f;
    #pragma unroll 8
    for (int u = 0; u < 64; ++u) {
        float ws = Ws[u * 64 + lane];
        float wv = Wv[u * 64 + lane];
        as += nsp[u] * ws;
        a0 += nvp[u * 3 + 0] * wv;
        a1 += nvp[u * 3 + 1] * wv;
        a2 += nvp[u * 3 + 2] * wv;
    }
    s_out[(size_t)n * 64 + lane] = as * LIN_NORM;
    v_out[0 * (size_t)N_NODES * 64 + (size_t)n * 64 + lane] = a0 * LIN_NORM;
    v_out[1 * (size_t)N_NODES * 64 + (size_t)n * 64 + lane] = a1 * LIN_NORM;
    v_out[2 * (size_t)N_NODES * 64 + (size_t)n * 64 + lane] = a2 * LIN_NORM;
}

// ---------------------------------------------------------------------------
// Kernel B: edge MLP + tensor product over DST-SORTED permutation.
// EB=8 edges/wave; cross-lane broadcasts via v_readlane (no LDS);
// per-edge scalars (emb, sh, src) via wave-uniform scalar loads.
// ---------------------------------------------------------------------------
#define EB 8

__global__ __launch_bounds__(256) void k_edge_sorted(
    const float* __restrict__ emb, const float* __restrict__ sh,
    const int* __restrict__ esrc,
    const int* __restrict__ elist, const int* __restrict__ dlist,
    const float* __restrict__ W0, const float* __restrict__ W1,
    const float* __restrict__ W2,
    const float* __restrict__ s_in, const float* __restrict__ v_in,
    float* __restrict__ s_agg, float* __restrict__ v_agg)
{
    const size_t NP2 = (size_t)N_NODES * 128;
    const size_t NV  = (size_t)N_NODES * 64;
    int lane = threadIdx.x & 63;
    int gwave = (blockIdx.x * blockDim.x + threadIdx.x) >> 6;
    int base = __builtin_amdgcn_readfirstlane(gwave * EB);
    if (base >= N_EDGES) return;

    int eids[EB], dsts[EB], srcs[EB];
    #pragma unroll
    for (int e = 0; e < EB; ++e) {
        eids[e] = __builtin_amdgcn_readfirstlane(elist[base + e]);
        dsts[e] = __builtin_amdgcn_readfirstlane(dlist[base + e]);
        srcs[e] = __builtin_amdgcn_readfirstlane(esrc[eids[e]]);
    }

    // ---- fc0: weights preloaded to 8 VGPRs; emb via uniform scalar loads
    float w0r[8];
    #pragma unroll
    for (int k = 0; k < 8; ++k) w0r[k] = W0[k * 64 + lane];
    float h[EB];
    #pragma unroll
    for (int e = 0; e < EB; ++e) {
        const float* ep = emb + (size_t)eids[e] * 8;
        float a = 0.f;
        #pragma unroll
        for (int k = 0; k < 8; ++k) a += ep[k] * w0r[k];
        h[e] = silu_n(a * INV_SQRT8);
    }

    // ---- fc1: acc[e] += readlane(h[e],k) * W1[k][lane]
    float acc[EB];
    #pragma unroll
    for (int e = 0; e < EB; ++e) acc[e] = 0.f;
    for (int k0 = 0; k0 < 64; k0 += 8) {
        #pragma unroll
        for (int i = 0; i < 8; ++i) {
            int k = k0 + i;
            float wv = W1[k * 64 + lane];
            #pragma unroll
            for (int e = 0; e < EB; ++e)
                acc[e] += bcast(h[e], k) * wv;
        }
    }
    #pragma unroll
    for (int e = 0; e < EB; ++e) h[e] = silu_n(acc[e] * 0.125f);

    // ---- fc2: 4 output groups of 64
    float aw0[EB], aw1[EB], aw2[EB], aw3[EB];
    #pragma unroll
    for (int e = 0; e < EB; ++e) { aw0[e] = 0.f; aw1[e] = 0.f; aw2[e] = 0.f; aw3[e] = 0.f; }
    for (int k0 = 0; k0 < 64; k0 += 4) {
        #pragma unroll
        for (int i = 0; i < 4; ++i) {
            int k = k0 + i;
            float w0 = W2[k * 256 + lane];
            float w1 = W2[k * 256 + 64 + lane];
            float w2 = W2[k * 256 + 128 + lane];
            float w3 = W2[k * 256 + 192 + lane];
            #pragma unroll
            for (int e = 0; e < EB; ++e) {
                float hv = bcast(h[e], k);
                aw0[e] += hv * w0;
                aw1[e] += hv * w1;
                aw2[e] += hv * w2;
                aw3[e] += hv * w3;
            }
        }
    }

    // ---- tensor product + run-merged scatter
    float accA = 0.f, accD = 0.f;
    float aB0 = 0.f, aB1 = 0.f, aB2 = 0.f;
    float aC0 = 0.f, aC1 = 0.f, aC2 = 0.f;

    auto flush = [&](int d) {
        size_t db = (size_t)d * 128;
        atomicAdd(&s_agg[db + lane],              accA * INV_NEIGH);
        atomicAdd(&s_agg[db + 64 + lane],         accD * INV_NEIGH);
        atomicAdd(&v_agg[0 * NP2 + db + lane],      aB0 * INV_NEIGH);
        atomicAdd(&v_agg[1 * NP2 + db + lane],      aB1 * INV_NEIGH);
        atomicAdd(&v_agg[2 * NP2 + db + lane],      aB2 * INV_NEIGH);
        atomicAdd(&v_agg[0 * NP2 + db + 64 + lane], aC0 * INV_NEIGH);
        atomicAdd(&v_agg[1 * NP2 + db + 64 + lane], aC1 * INV_NEIGH);
        atomicAdd(&v_agg[2 * NP2 + db + 64 + lane], aC2 * INV_NEIGH);
        accA = accD = aB0 = aB1 = aB2 = aC0 = aC1 = aC2 = 0.f;
    };

    int cur = dsts[0];
    const float4* sh4 = (const float4*)sh;
    #pragma unroll
    for (int e = 0; e < EB; ++e) {
        if (dsts[e] != cur) { flush(cur); cur = dsts[e]; }
        int eid = eids[e];
        int src = srcs[e];
        float4 y = sh4[eid];                    // uniform address -> s_load
        float se = s_in[(size_t)src * 64 + lane];
        float v0 = v_in[0 * NV + (size_t)src * 64 + lane];
        float v1 = v_in[1 * NV + (size_t)src * 64 + lane];
        float v2 = v_in[2 * NV + (size_t)src * 64 + lane];
        float wA = aw0[e] * 0.125f;
        float wB = aw1[e] * 0.125f;
        float wC = aw2[e] * 0.125f;
        float wD = aw3[e] * 0.125f;

        accA += wA * se * y.x;
        float dot = v0 * y.y + v1 * y.z + v2 * y.w;
        accD += wD * dot * INV_SQRT3;
        float bB = wB * se;
        aB0 += bB * y.y;
        aB1 += bB * y.z;
        aB2 += bB * y.w;
        float bC = wC * y.x;
        aC0 += bC * v0;
        aC1 += bC * v1;
        aC2 += bC * v2;
    }
    flush(cur);
}

// ---------------------------------------------------------------------------
// Kernel C: per-node epilogue.  Activations via wave-uniform scalar loads;
// weights lane-coalesced; no shuffles.  NB=4 nodes per wave.
// ---------------------------------------------------------------------------
#define NB 4

__global__ __launch_bounds__(256) void k_node_out(
    const float* __restrict__ ns, const float* __restrict__ nv,
    const float* __restrict__ na,
    const float* __restrict__ Wl2s, const float* __restrict__ Wl2v,
    const float* __restrict__ Wscs, const float* __restrict__ Wscv,
    const float* __restrict__ s_agg, const float* __restrict__ v_agg,
    float* __restrict__ out)
{
    const size_t NP2 = (size_t)N_NODES * 128;
    int lane = threadIdx.x & 63;
    int gwave = (blockIdx.x * blockDim.x + threadIdx.x) >> 6;
    int n0 = __builtin_amdgcn_readfirstlane(gwave * NB);
    if (n0 >= N_NODES) return;

    float sA[NB], sB[NB], vh[NB][3];
    #pragma unroll
    for (int j = 0; j < NB; ++j) {
        sA[j] = 0.f; sB[j] = 0.f;
        vh[j][0] = 0.f; vh[j][1] = 0.f; vh[j][2] = 0.f;
    }

    // lin2 (s and v fused over the 128 aggregated channels)
    for (int u0 = 0; u0 < 128; u0 += 8) {
        #pragma unroll
        for (int i = 0; i < 8; ++i) {
            int u = u0 + i;
            float w1 = Wl2s[u * 128 + lane];
            float w2 = Wl2s[u * 128 + 64 + lane];
            float wv = Wl2v[u * 64 + lane];
            #pragma unroll
            for (int j = 0; j < NB; ++j) {
                size_t nj = (size_t)(n0 + j);
                float a = s_agg[nj * 128 + u];                 // scalar load
                sA[j] += a * w1; sB[j] += a * w2;
                vh[j][0] += v_agg[0 * NP2 + nj * 128 + u] * wv;
                vh[j][1] += v_agg[1 * NP2 + nj * 128 + u] * wv;
                vh[j][2] += v_agg[2 * NP2 + nj * 128 + u] * wv;
            }
        }
    }
    #pragma unroll
    for (int j = 0; j < NB; ++j) {
        sA[j] *= LIN2_NORM; sB[j] *= LIN2_NORM;
        vh[j][0] *= LIN2_NORM; vh[j][1] *= LIN2_NORM; vh[j][2] *= LIN2_NORM;
    }

    // self-connection (fused)
    float pa[NB][4];
    #pragma unroll
    for (int j = 0; j < NB; ++j)
        #pragma unroll
        for (int q = 0; q < 4; ++q)
            pa[j][q] = na[(size_t)(n0 + j) * 4 + q] * SC_NORM;

    for (int u0 = 0; u0 < 64; u0 += 4) {
        #pragma unroll
        for (int i = 0; i < 4; ++i) {
            int u = u0 + i;
            #pragma unroll
            for (int q = 0; q < 4; ++q) {
                int idx = u * 4 + q;
                float wss1 = Wscs[idx * 128 + lane];
                float wss2 = Wscs[idx * 128 + 64 + lane];
                float wsv  = Wscv[idx * 64 + lane];
                #pragma unroll
                for (int j = 0; j < NB; ++j) {
                    size_t nj = (size_t)(n0 + j);
                    float su = ns[nj * 64 + u];                // scalar load
                    float t = su * pa[j][q];
                    sA[j] += t * wss1;
                    sB[j] += t * wss2;
                    float tq = pa[j][q] * wsv;
                    vh[j][0] += nv[nj * 192 + u * 3 + 0] * tq;
                    vh[j][1] += nv[nj * 192 + u * 3 + 1] * tq;
                    vh[j][2] += nv[nj * 192 + u * 3 + 2] * tq;
                }
            }
        }
    }

    // epilogue + store
    #pragma unroll
    for (int j = 0; j < NB; ++j) {
        int n = n0 + j;
        float os = silu_n(sA[j]);
        float g  = silu_n(sB[j]);
        out[(size_t)n * 256 + lane] = os;
        out[(size_t)n * 256 + 64 + lane * 3 + 0] = g * vh[j][0];
        out[(size_t)n * 256 + 64 + lane * 3 + 1] = g * vh[j][1];
        out[(size_t)n * 256 + 64 + lane * 3 + 2] = g * vh[j][2];
    }
}

// ---------------------------------------------------------------------------
extern "C" void kernel_launch(void* const* d_in, const int* in_sizes, int n_in,
                              void* d_out, int out_size, void* d_ws, size_t ws_size,
                              hipStream_t stream)
{
    const float* node_scalars = (const float*)d_in[0];
    const float* node_vectors = (const float*)d_in[1];
    const float* node_attr    = (const float*)d_in[2];
    const float* edge_sh      = (const float*)d_in[3];
    const float* edge_emb     = (const float*)d_in[4];
    const int*   edge_src     = (const int*)d_in[5];
    const int*   edge_dst     = (const int*)d_in[6];
    const float* W_lin1_s = (const float*)d_in[7];
    const float* W_lin1_v = (const float*)d_in[8];
    const float* W_fc0    = (const float*)d_in[9];
    const float* W_fc1    = (const float*)d_in[10];
    const float* W_fc2    = (const float*)d_in[11];
    const float* W_lin2_s = (const float*)d_in[12];
    const float* W_lin2_v = (const float*)d_in[13];
    const float* W_sc_s   = (const float*)d_in[14];
    const float* W_sc_v   = (const float*)d_in[15];
    float* out = (float*)d_out;

    // workspace layout
    float* ws    = (float*)d_ws;
    float* s_buf = ws;                                    // N*64
    float* v_buf = s_buf + (size_t)N_NODES * 64;          // 3*N*64
    float* s_agg = v_buf + 3 * (size_t)N_NODES * 64;      // N*128
    float* v_agg = s_agg + (size_t)N_NODES * 128;         // 3*N*128
    int*   counts = (int*)(v_agg + 3 * (size_t)N_NODES * 128);  // N
    int*   cursor = counts + N_NODES;                     // N
    int*   elist  = cursor + N_NODES;                     // E
    int*   dlist  = elist + N_EDGES;                      // E

    hipMemsetAsync(s_agg, 0, (size_t)N_NODES * 512 * sizeof(float), stream);
    hipMemsetAsync(counts, 0, (size_t)N_NODES * sizeof(int), stream);

    // CSR build
    {
        int blocks = (N_EDGES + 255) / 256;
        k_hist<<<blocks, 256, 0, stream>>>(edge_dst, counts);
        k_scan<<<1, SCAN_T, 0, stream>>>(counts, cursor);
        k_fill<<<blocks, 256, 0, stream>>>(edge_dst, cursor, elist, dlist);
    }
    // A: node lin1 (one wave per node)
    {
        int blocks = (N_NODES + 3) / 4;
        k_node_lin1<<<blocks, 256, 0, stream>>>(node_scalars, node_vectors,
                                                W_lin1_s, W_lin1_v, s_buf, v_buf);
    }
    // B: edges over sorted permutation
    {
        int waves = (N_EDGES + EB - 1) / EB;   // 40000
        int blocks = (waves + 3) / 4;          // 10000
        k_edge_sorted<<<blocks, 256, 0, stream>>>(edge_emb, edge_sh, edge_src,
                                                  elist, dlist,
                                                  W_fc0, W_fc1, W_fc2,
                                                  s_buf, v_buf, s_agg, v_agg);
    }
    // C: node epilogue
    {
        int waves = (N_NODES + NB - 1) / NB;   // 5000
        int blocks = (waves + 3) / 4;          // 1250
        k_node_out<<<blocks, 256, 0, stream>>>(node_scalars, node_vectors, node_attr,
                                               W_lin2_s, W_lin2_v, W_sc_s, W_sc_v,
                                               s_agg, v_agg, out);
    }
}

// Round 4
// 687.830 us; speedup vs baseline: 1.3287x; 1.0218x over previous
//
#include <hip/hip_runtime.h>
#include <math.h>

#define N_NODES 20000
#define N_EDGES 320000
#define MUL 64
#define NUM_BASIS 8
#define HID 64
#define NSPEC 4

#define LIN_NORM     0.125f          // 1/sqrt(64)
#define INV_SQRT8    0.3535533906f   // 1/sqrt(8)
#define LIN2_NORM    0.08838834765f  // 1/sqrt(128)
#define SC_NORM      0.0625f         // 1/sqrt(64*4)
#define INV_NEIGH    0.0625f         // 1/16
#define INV_SQRT3    0.5773502692f
#define SILU_NORM    1.679177f

__device__ __forceinline__ float silu_n(float x) {
    float s = 1.0f / (1.0f + __expf(-x));
    return x * s * SILU_NORM;
}

// broadcast from (uniform) lane l via v_readlane — no LDS pipe traffic.
__device__ __forceinline__ float bcast(float x, int l) {
    return __uint_as_float(__builtin_amdgcn_readlane(__float_as_uint(x), l));
}

// ---------------------------------------------------------------------------
// CSR build: histogram -> 1-block scan -> scatter (permutation sorted by dst)
// ---------------------------------------------------------------------------
__global__ __launch_bounds__(256) void k_hist(const int* __restrict__ edst,
                                              int* __restrict__ counts)
{
    int e = blockIdx.x * blockDim.x + threadIdx.x;
    if (e < N_EDGES) atomicAdd(&counts[edst[e]], 1);
}

#define SCAN_T 1024
__global__ __launch_bounds__(SCAN_T) void k_scan(const int* __restrict__ counts,
                                                 int* __restrict__ cursor)
{
    __shared__ int part[SCAN_T];
    int t = threadIdx.x;
    const int CH = (N_NODES + SCAN_T - 1) / SCAN_T;   // 20
    int b0 = t * CH;
    int s = 0;
    for (int i = 0; i < CH; ++i) {
        int idx = b0 + i;
        if (idx < N_NODES) s += counts[idx];
    }
    part[t] = s;
    __syncthreads();
    for (int off = 1; off < SCAN_T; off <<= 1) {
        int v = (t >= off) ? part[t - off] : 0;
        __syncthreads();
        part[t] += v;
        __syncthreads();
    }
    int run = (t == 0) ? 0 : part[t - 1];
    for (int i = 0; i < CH; ++i) {
        int idx = b0 + i;
        if (idx < N_NODES) {
            cursor[idx] = run;
            run += counts[idx];
        }
    }
}

__global__ __launch_bounds__(256) void k_fill(const int* __restrict__ edst,
                                              int* __restrict__ cursor,
                                              int* __restrict__ elist,
                                              int* __restrict__ dlist)
{
    int e = blockIdx.x * blockDim.x + threadIdx.x;
    if (e < N_EDGES) {
        int d = edst[e];
        int pos = atomicAdd(&cursor[d], 1);
        elist[pos] = e;
        dlist[pos] = d;
    }
}

// ---------------------------------------------------------------------------
// Kernel A: per-node lin1. Activations via wave-uniform scalar loads;
// weights lane-coalesced. v stored planar: v[p][n][u]
// ---------------------------------------------------------------------------
__global__ __launch_bounds__(256) void k_node_lin1(
    const float* __restrict__ ns, const float* __restrict__ nv,
    const float* __restrict__ Ws, const float* __restrict__ Wv,
    float* __restrict__ s_out, float* __restrict__ v_out)
{
    int lane = threadIdx.x & 63;
    int gwave = (blockIdx.x * blockDim.x + threadIdx.x) >> 6;
    int n = __builtin_amdgcn_readfirstlane(gwave);
    if (n >= N_NODES) return;
    const float* nsp = ns + (size_t)n * 64;
    const float* nvp = nv + (size_t)n * 192;
    float as = 0.f, a0 = 0.f, a1 = 0.f, a2 = 0.f;
    #pragma unroll 8
    for (int u = 0; u < 64; ++u) {
        float ws = Ws[u * 64 + lane];
        float wv = Wv[u * 64 + lane];
        as += nsp[u] * ws;
        a0 += nvp[u * 3 + 0] * wv;
        a1 += nvp[u * 3 + 1] * wv;
        a2 += nvp[u * 3 + 2] * wv;
    }
    s_out[(size_t)n * 64 + lane] = as * LIN_NORM;
    v_out[0 * (size_t)N_NODES * 64 + (size_t)n * 64 + lane] = a0 * LIN_NORM;
    v_out[1 * (size_t)N_NODES * 64 + (size_t)n * 64 + lane] = a1 * LIN_NORM;
    v_out[2 * (size_t)N_NODES * 64 + (size_t)n * 64 + lane] = a2 * LIN_NORM;
}

// ---------------------------------------------------------------------------
// Kernel B: edge MLP + tensor product over DST-SORTED permutation.
// EB=8 edges/wave; broadcasts via v_readlane; HW fp32 atomics (no CAS loop).
// ---------------------------------------------------------------------------
#define EB 8

__global__ __launch_bounds__(256) void k_edge_sorted(
    const float* __restrict__ emb, const float* __restrict__ sh,
    const int* __restrict__ esrc,
    const int* __restrict__ elist, const int* __restrict__ dlist,
    const float* __restrict__ W0, const float* __restrict__ W1,
    const float* __restrict__ W2,
    const float* __restrict__ s_in, const float* __restrict__ v_in,
    float* __restrict__ s_agg, float* __restrict__ v_agg)
{
    const size_t NP2 = (size_t)N_NODES * 128;
    const size_t NV  = (size_t)N_NODES * 64;
    int lane = threadIdx.x & 63;
    int gwave = (blockIdx.x * blockDim.x + threadIdx.x) >> 6;
    int base = __builtin_amdgcn_readfirstlane(gwave * EB);
    if (base >= N_EDGES) return;

    int eids[EB], dsts[EB], srcs[EB];
    #pragma unroll
    for (int e = 0; e < EB; ++e) {
        eids[e] = __builtin_amdgcn_readfirstlane(elist[base + e]);
        dsts[e] = __builtin_amdgcn_readfirstlane(dlist[base + e]);
        srcs[e] = __builtin_amdgcn_readfirstlane(esrc[eids[e]]);
    }

    // ---- fc0
    float w0r[8];
    #pragma unroll
    for (int k = 0; k < 8; ++k) w0r[k] = W0[k * 64 + lane];
    float h[EB];
    #pragma unroll
    for (int e = 0; e < EB; ++e) {
        const float* ep = emb + (size_t)eids[e] * 8;
        float a = 0.f;
        #pragma unroll
        for (int k = 0; k < 8; ++k) a += ep[k] * w0r[k];
        h[e] = silu_n(a * INV_SQRT8);
    }

    // ---- fc1
    float acc[EB];
    #pragma unroll
    for (int e = 0; e < EB; ++e) acc[e] = 0.f;
    for (int k0 = 0; k0 < 64; k0 += 8) {
        #pragma unroll
        for (int i = 0; i < 8; ++i) {
            int k = k0 + i;
            float wv = W1[k * 64 + lane];
            #pragma unroll
            for (int e = 0; e < EB; ++e)
                acc[e] += bcast(h[e], k) * wv;
        }
    }
    #pragma unroll
    for (int e = 0; e < EB; ++e) h[e] = silu_n(acc[e] * 0.125f);

    // ---- fc2 (4 output groups of 64)
    float aw0[EB], aw1[EB], aw2[EB], aw3[EB];
    #pragma unroll
    for (int e = 0; e < EB; ++e) { aw0[e] = 0.f; aw1[e] = 0.f; aw2[e] = 0.f; aw3[e] = 0.f; }
    for (int k0 = 0; k0 < 64; k0 += 4) {
        #pragma unroll
        for (int i = 0; i < 4; ++i) {
            int k = k0 + i;
            float w0 = W2[k * 256 + lane];
            float w1 = W2[k * 256 + 64 + lane];
            float w2 = W2[k * 256 + 128 + lane];
            float w3 = W2[k * 256 + 192 + lane];
            #pragma unroll
            for (int e = 0; e < EB; ++e) {
                float hv = bcast(h[e], k);
                aw0[e] += hv * w0;
                aw1[e] += hv * w1;
                aw2[e] += hv * w2;
                aw3[e] += hv * w3;
            }
        }
    }

    // ---- tensor product + run-merged scatter (HW fp32 atomics)
    float accA = 0.f, accD = 0.f;
    float aB0 = 0.f, aB1 = 0.f, aB2 = 0.f;
    float aC0 = 0.f, aC1 = 0.f, aC2 = 0.f;

    auto flush = [&](int d) {
        size_t db = (size_t)d * 128;
        unsafeAtomicAdd(&s_agg[db + lane],              accA);
        unsafeAtomicAdd(&s_agg[db + 64 + lane],         accD);
        unsafeAtomicAdd(&v_agg[0 * NP2 + db + lane],      aB0);
        unsafeAtomicAdd(&v_agg[1 * NP2 + db + lane],      aB1);
        unsafeAtomicAdd(&v_agg[2 * NP2 + db + lane],      aB2);
        unsafeAtomicAdd(&v_agg[0 * NP2 + db + 64 + lane], aC0);
        unsafeAtomicAdd(&v_agg[1 * NP2 + db + 64 + lane], aC1);
        unsafeAtomicAdd(&v_agg[2 * NP2 + db + 64 + lane], aC2);
        accA = accD = aB0 = aB1 = aB2 = aC0 = aC1 = aC2 = 0.f;
    };

    const float WSCALE = 0.125f * INV_NEIGH;   // fold /16 into the weights
    int cur = dsts[0];
    const float4* sh4 = (const float4*)sh;
    #pragma unroll
    for (int e = 0; e < EB; ++e) {
        if (dsts[e] != cur) { flush(cur); cur = dsts[e]; }
        int eid = eids[e];
        int src = srcs[e];
        float4 y = sh4[eid];                    // uniform address -> s_load
        float se = s_in[(size_t)src * 64 + lane];
        float v0 = v_in[0 * NV + (size_t)src * 64 + lane];
        float v1 = v_in[1 * NV + (size_t)src * 64 + lane];
        float v2 = v_in[2 * NV + (size_t)src * 64 + lane];
        float wA = aw0[e] * WSCALE;
        float wB = aw1[e] * WSCALE;
        float wC = aw2[e] * WSCALE;
        float wD = aw3[e] * WSCALE;

        accA += wA * se * y.x;
        float dot = v0 * y.y + v1 * y.z + v2 * y.w;
        accD += wD * dot * INV_SQRT3;
        float bB = wB * se;
        aB0 += bB * y.y;
        aB1 += bB * y.z;
        aB2 += bB * y.w;
        float bC = wC * y.x;
        aC0 += bC * v0;
        aC1 += bC * v1;
        aC2 += bC * v2;
    }
    flush(cur);
}

// ---------------------------------------------------------------------------
// Kernel C: per-node epilogue. Activations loaded lane-parallel (coalesced),
// broadcast via v_readlane; weights lane-coalesced. NB=4 nodes per wave.
// ---------------------------------------------------------------------------
#define NB 4

__global__ __launch_bounds__(256) void k_node_out(
    const float* __restrict__ ns, const float* __restrict__ nv,
    const float* __restrict__ na,
    const float* __restrict__ Wl2s, const float* __restrict__ Wl2v,
    const float* __restrict__ Wscs, const float* __restrict__ Wscv,
    const float* __restrict__ s_agg, const float* __restrict__ v_agg,
    float* __restrict__ out)
{
    const size_t NP2 = (size_t)N_NODES * 128;
    int lane = threadIdx.x & 63;
    int gwave = (blockIdx.x * blockDim.x + threadIdx.x) >> 6;
    int n0 = __builtin_amdgcn_readfirstlane(gwave * NB);
    if (n0 >= N_NODES) return;

    // lane-parallel activation preloads (lane = channel)
    float aL[NB], aH[NB], bL[3][NB], bH[3][NB], su_r[NB], vu_r[3][NB];
    float pa[NB][4];
    #pragma unroll
    for (int j = 0; j < NB; ++j) {
        size_t nj = (size_t)(n0 + j);
        aL[j] = s_agg[nj * 128 + lane];
        aH[j] = s_agg[nj * 128 + 64 + lane];
        #pragma unroll
        for (int p = 0; p < 3; ++p) {
            bL[p][j] = v_agg[p * NP2 + nj * 128 + lane];
            bH[p][j] = v_agg[p * NP2 + nj * 128 + 64 + lane];
            vu_r[p][j] = nv[nj * 192 + lane * 3 + p];
        }
        su_r[j] = ns[nj * 64 + lane];
        #pragma unroll
        for (int q = 0; q < 4; ++q)
            pa[j][q] = na[nj * 4 + q] * SC_NORM;
    }

    float sA[NB], sB[NB], vh[NB][3];
    #pragma unroll
    for (int j = 0; j < NB; ++j) {
        sA[j] = 0.f; sB[j] = 0.f;
        vh[j][0] = 0.f; vh[j][1] = 0.f; vh[j][2] = 0.f;
    }

    // lin2 over first 64 aggregated channels
    for (int u0 = 0; u0 < 64; u0 += 8) {
        #pragma unroll
        for (int i = 0; i < 8; ++i) {
            int u = u0 + i;
            float w1 = Wl2s[u * 128 + lane];
            float w2 = Wl2s[u * 128 + 64 + lane];
            float wv = Wl2v[u * 64 + lane];
            #pragma unroll
            for (int j = 0; j < NB; ++j) {
                float av = bcast(aL[j], u);
                sA[j] += av * w1; sB[j] += av * w2;
                vh[j][0] += bcast(bL[0][j], u) * wv;
                vh[j][1] += bcast(bL[1][j], u) * wv;
                vh[j][2] += bcast(bL[2][j], u) * wv;
            }
        }
    }
    // lin2 over upper 64 aggregated channels
    for (int u0 = 0; u0 < 64; u0 += 8) {
        #pragma unroll
        for (int i = 0; i < 8; ++i) {
            int u = u0 + i;
            float w1 = Wl2s[(64 + u) * 128 + lane];
            float w2 = Wl2s[(64 + u) * 128 + 64 + lane];
            float wv = Wl2v[(64 + u) * 64 + lane];
            #pragma unroll
            for (int j = 0; j < NB; ++j) {
                float av = bcast(aH[j], u);
                sA[j] += av * w1; sB[j] += av * w2;
                vh[j][0] += bcast(bH[0][j], u) * wv;
                vh[j][1] += bcast(bH[1][j], u) * wv;
                vh[j][2] += bcast(bH[2][j], u) * wv;
            }
        }
    }
    #pragma unroll
    for (int j = 0; j < NB; ++j) {
        sA[j] *= LIN2_NORM; sB[j] *= LIN2_NORM;
        vh[j][0] *= LIN2_NORM; vh[j][1] *= LIN2_NORM; vh[j][2] *= LIN2_NORM;
    }

    // self-connection (fused)
    for (int u0 = 0; u0 < 64; u0 += 4) {
        #pragma unroll
        for (int i = 0; i < 4; ++i) {
            int u = u0 + i;
            float suv[NB], vuv[3][NB];
            #pragma unroll
            for (int j = 0; j < NB; ++j) {
                suv[j] = bcast(su_r[j], u);
                vuv[0][j] = bcast(vu_r[0][j], u);
                vuv[1][j] = bcast(vu_r[1][j], u);
                vuv[2][j] = bcast(vu_r[2][j], u);
            }
            #pragma unroll
            for (int q = 0; q < 4; ++q) {
                int idx = u * 4 + q;
                float wss1 = Wscs[idx * 128 + lane];
                float wss2 = Wscs[idx * 128 + 64 + lane];
                float wsv  = Wscv[idx * 64 + lane];
                #pragma unroll
                for (int j = 0; j < NB; ++j) {
                    float t = suv[j] * pa[j][q];
                    sA[j] += t * wss1;
                    sB[j] += t * wss2;
                    float tq = pa[j][q] * wsv;
                    vh[j][0] += vuv[0][j] * tq;
                    vh[j][1] += vuv[1][j] * tq;
                    vh[j][2] += vuv[2][j] * tq;
                }
            }
        }
    }

    // epilogue + store
    #pragma unroll
    for (int j = 0; j < NB; ++j) {
        int n = n0 + j;
        float os = silu_n(sA[j]);
        float g  = silu_n(sB[j]);
        out[(size_t)n * 256 + lane] = os;
        out[(size_t)n * 256 + 64 + lane * 3 + 0] = g * vh[j][0];
        out[(size_t)n * 256 + 64 + lane * 3 + 1] = g * vh[j][1];
        out[(size_t)n * 256 + 64 + lane * 3 + 2] = g * vh[j][2];
    }
}

// ---------------------------------------------------------------------------
extern "C" void kernel_launch(void* const* d_in, const int* in_sizes, int n_in,
                              void* d_out, int out_size, void* d_ws, size_t ws_size,
                              hipStream_t stream)
{
    const float* node_scalars = (const float*)d_in[0];
    const float* node_vectors = (const float*)d_in[1];
    const float* node_attr    = (const float*)d_in[2];
    const float* edge_sh      = (const float*)d_in[3];
    const float* edge_emb     = (const float*)d_in[4];
    const int*   edge_src     = (const int*)d_in[5];
    const int*   edge_dst     = (const int*)d_in[6];
    const float* W_lin1_s = (const float*)d_in[7];
    const float* W_lin1_v = (const float*)d_in[8];
    const float* W_fc0    = (const float*)d_in[9];
    const float* W_fc1    = (const float*)d_in[10];
    const float* W_fc2    = (const float*)d_in[11];
    const float* W_lin2_s = (const float*)d_in[12];
    const float* W_lin2_v = (const float*)d_in[13];
    const float* W_sc_s   = (const float*)d_in[14];
    const float* W_sc_v   = (const float*)d_in[15];
    float* out = (float*)d_out;

    // workspace layout
    float* ws    = (float*)d_ws;
    float* s_buf = ws;                                    // N*64
    float* v_buf = s_buf + (size_t)N_NODES * 64;          // 3*N*64
    float* s_agg = v_buf + 3 * (size_t)N_NODES * 64;      // N*128
    float* v_agg = s_agg + (size_t)N_NODES * 128;         // 3*N*128
    int*   counts = (int*)(v_agg + 3 * (size_t)N_NODES * 128);  // N
    int*   cursor = counts + N_NODES;                     // N
    int*   elist  = cursor + N_NODES;                     // E
    int*   dlist  = elist + N_EDGES;                      // E

    hipMemsetAsync(s_agg, 0, (size_t)N_NODES * 512 * sizeof(float), stream);
    hipMemsetAsync(counts, 0, (size_t)N_NODES * sizeof(int), stream);

    // CSR build
    {
        int blocks = (N_EDGES + 255) / 256;
        k_hist<<<blocks, 256, 0, stream>>>(edge_dst, counts);
        k_scan<<<1, SCAN_T, 0, stream>>>(counts, cursor);
        k_fill<<<blocks, 256, 0, stream>>>(edge_dst, cursor, elist, dlist);
    }
    // A: node lin1 (one wave per node)
    {
        int blocks = (N_NODES + 3) / 4;
        k_node_lin1<<<blocks, 256, 0, stream>>>(node_scalars, node_vectors,
                                                W_lin1_s, W_lin1_v, s_buf, v_buf);
    }
    // B: edges over sorted permutation
    {
        int waves = (N_EDGES + EB - 1) / EB;   // 40000
        int blocks = (waves + 3) / 4;          // 10000
        k_edge_sorted<<<blocks, 256, 0, stream>>>(edge_emb, edge_sh, edge_src,
                                                  elist, dlist,
                                                  W_fc0, W_fc1, W_fc2,
                                                  s_buf, v_buf, s_agg, v_agg);
    }
    // C: node epilogue
    {
        int waves = (N_NODES + NB - 1) / NB;   // 5000
        int blocks = (waves + 3) / 4;          // 1250
        k_node_out<<<blocks, 256, 0, stream>>>(node_scalars, node_vectors, node_attr,
                                               W_lin2_s, W_lin2_v, W_sc_s, W_sc_v,
                                               s_agg, v_agg, out);
    }
}